// Round 3
// baseline (8387.518 us; speedup 1.0000x reference)
//
#include <hip/hip_runtime.h>
#include <math.h>

#define NEGBIG (-1e30f)

// Sizes: B=512, S=8, U=512, D=32, G=8, DIM_IN=4096, DAG=2048
// out layout: att[512*16384] | ga[512*2048] | w[512^3] | outputs[512*16384]

// ---------------- K1/K2: per-split fp32 GEMM (64x64 tile, Kstep 16) ----------------
__global__ __launch_bounds__(256) void gemm_split(
    const float* __restrict__ A, int lda, int Ksz,
    const float* __restrict__ Bw, int NS,
    const float* __restrict__ bias,
    float* __restrict__ C, int ldc)
{
  const int n0 = blockIdx.x * 64;
  const int b0 = blockIdx.y * 64;
  const int s  = n0 / NS;
  const float* Bp = Bw + (size_t)s * Ksz * NS;
  const int nloc0 = n0 - s * NS;
  const int acol0 = s * Ksz;

  __shared__ float As[16][64];
  __shared__ float Bs[16][64];

  const int t  = threadIdx.x;
  const int tb = t & 15, tn = t >> 4;
  float acc[4][4] = {};

  for (int k0 = 0; k0 < Ksz; k0 += 16) {
    {
      int r = t & 63, g = t >> 6;
      float4 v = *reinterpret_cast<const float4*>(
          A + (size_t)(b0 + r) * lda + acol0 + k0 + 4 * g);
      As[4*g+0][r] = v.x; As[4*g+1][r] = v.y; As[4*g+2][r] = v.z; As[4*g+3][r] = v.w;
    }
    {
      int kk = t >> 4, n4 = t & 15;
      float4 v = *reinterpret_cast<const float4*>(
          Bp + (size_t)(k0 + kk) * NS + nloc0 + 4 * n4);
      *reinterpret_cast<float4*>(&Bs[kk][4*n4]) = v;
    }
    __syncthreads();
#pragma unroll
    for (int k = 0; k < 16; ++k) {
      float4 a4 = *reinterpret_cast<const float4*>(&As[k][4*tb]);
      float4 b4 = *reinterpret_cast<const float4*>(&Bs[k][4*tn]);
      float av[4] = {a4.x, a4.y, a4.z, a4.w};
      float bv[4] = {b4.x, b4.y, b4.z, b4.w};
#pragma unroll
      for (int i = 0; i < 4; ++i)
#pragma unroll
        for (int j = 0; j < 4; ++j)
          acc[i][j] = fmaf(av[i], bv[j], acc[i][j]);
    }
    __syncthreads();
  }
#pragma unroll
  for (int i = 0; i < 4; ++i) {
    int row = b0 + 4*tb + i;
    int col = n0 + 4*tn;
    float4 o;
    o.x = acc[i][0] + bias[col + 0];
    o.y = acc[i][1] + bias[col + 1];
    o.z = acc[i][2] + bias[col + 2];
    o.w = acc[i][3] + bias[col + 3];
    *reinterpret_cast<float4*>(C + (size_t)row * ldc + col) = o;
  }
}

// ---------------- fused back half ----------------
// thread = (b,u): att row in 8 f4 regs; M/L per group in regs; outputs acc in 8 f4 regs.
// pass 1: stream m, masked scores -> online (M,L).  pass 2: recompute identical score,
// re-read rnd for mask, w = exp(s-M)*1/(8L) (masked -> 0), accumulate outputs.
// LDS: ma/mo chunk [16 m][16 u][36 f] padded rows (9 f4 -> <=2-way conflicts). 72 KB.

__device__ __forceinline__ float dot32(const float4 A[8], const float* base) {
  float s0 = 0.f, s1 = 0.f, s2 = 0.f, s3 = 0.f;
#pragma unroll
  for (int k = 0; k < 8; ++k) {
    float4 q = *reinterpret_cast<const float4*>(base + 4 * k);
    s0 = fmaf(A[k].x, q.x, s0);
    s1 = fmaf(A[k].y, q.y, s1);
    s2 = fmaf(A[k].z, q.z, s2);
    s3 = fmaf(A[k].w, q.w, s3);
  }
  return (s0 + s2) + (s1 + s3);
}

__global__ __launch_bounds__(256, 2) void fused_back_kernel(
    const float* __restrict__ att, const float* __restrict__ ma,
    const float* __restrict__ mo, const float* __restrict__ rnd,
    const float* __restrict__ temp,
    float* __restrict__ w, float* __restrict__ outs)
{
  __shared__ float MaL[16 * 16 * 36];   // 36 KB
  __shared__ float MoL[16 * 16 * 36];   // 36 KB

  const int bid = blockIdx.x;
  const int wk = ((bid & 7) << 7) | (bid >> 3);   // XCD-chunked (1024 % 8 == 0)
  const int b0 = (wk & 31) * 16, u0 = (wk >> 5) * 16;
  const int t = threadIdx.x;
  const int u = t & 15, tb = t >> 4;
  const int gb = b0 + tb, gu = u0 + u;

  float4 A[8];
  {
    const float* ar = att + ((size_t)gb * 512 + gu) * 32;
#pragma unroll
    for (int k = 0; k < 8; ++k)
      A[k] = *reinterpret_cast<const float4*>(ar + 4 * k);
  }
  const float tmp = temp[gu];
  const float* rbase = rnd + (size_t)gb * 262144 + gu;

  // staging descriptors: per thread 8 f4 per tensor per chunk; m = m_s + 2p
  const int u_s = (t >> 3) & 15, d4s = t & 7, m_s = t >> 7;
  const float* gma = ma + (size_t)m_s * 16384 + (size_t)(u0 + u_s) * 32 + 4 * d4s;
  const float* gmo = mo + (size_t)m_s * 16384 + (size_t)(u0 + u_s) * 32 + 4 * d4s;
  const int lbase = (m_s * 16 + u_s) * 36 + 4 * d4s;
  const float* mabase = &MaL[u * 36];   // + j*576 + 4k
  const float* mobase = &MoL[u * 36];

  float M[8], L[8];
#pragma unroll
  for (int g = 0; g < 8; ++g) { M[g] = NEGBIG; L[g] = 0.f; }

  // ---------------- pass 1: online stats ----------------
  float4 Sa[8], So[8];
  float rc[16], rn[16];
#pragma unroll
  for (int p = 0; p < 8; ++p)
    Sa[p] = *reinterpret_cast<const float4*>(gma + (size_t)(2 * p) * 16384);
#pragma unroll
  for (int j = 0; j < 16; ++j) rc[j] = rbase[(size_t)j * 512];

#pragma unroll 1
  for (int c = 0; c < 32; ++c) {
    const int m0 = c * 16;
    __syncthreads();
#pragma unroll
    for (int p = 0; p < 8; ++p)
      *reinterpret_cast<float4*>(&MaL[lbase + 1152 * p]) = Sa[p];
    if (c < 31) {   // prefetch chunk c+1: flies across the barrier during compute
#pragma unroll
      for (int p = 0; p < 8; ++p)
        Sa[p] = *reinterpret_cast<const float4*>(gma + (size_t)(m0 + 16 + 2 * p) * 16384);
#pragma unroll
      for (int j = 0; j < 16; ++j) rn[j] = rbase[(size_t)(m0 + 16 + j) * 512];
    }
    __syncthreads();
#pragma unroll
    for (int j = 0; j < 16; ++j) {
      float s = dot32(A, mabase + j * 576) * tmp;
      const int m = m0 + j;
      if ((rc[j] < 0.1f) | (m == gb)) s = NEGBIG;
      const int g = j & 7;
      float d = s - M[g];
      if (d > 0.f) { L[g] = fmaf(L[g], __expf(-d), 1.f); M[g] = s; }
      else          L[g] += __expf(d);
    }
#pragma unroll
    for (int j = 0; j < 16; ++j) rc[j] = rn[j];
  }

  float IL[8];
#pragma unroll
  for (int g = 0; g < 8; ++g) IL[g] = 1.0f / (8.0f * L[g]);

  // ---------------- pass 2: w emit + outputs ----------------
  float4 O[8];
#pragma unroll
  for (int k = 0; k < 8; ++k) O[k] = make_float4(0.f, 0.f, 0.f, 0.f);
#pragma unroll
  for (int p = 0; p < 8; ++p) {
    Sa[p] = *reinterpret_cast<const float4*>(gma + (size_t)(2 * p) * 16384);
    So[p] = *reinterpret_cast<const float4*>(gmo + (size_t)(2 * p) * 16384);
  }
#pragma unroll
  for (int j = 0; j < 16; ++j) rc[j] = rbase[(size_t)j * 512];

  float* wbase = w + (size_t)gb * 262144 + gu;

#pragma unroll 1
  for (int c = 0; c < 32; ++c) {
    const int m0 = c * 16;
    __syncthreads();
#pragma unroll
    for (int p = 0; p < 8; ++p) {
      *reinterpret_cast<float4*>(&MaL[lbase + 1152 * p]) = Sa[p];
      *reinterpret_cast<float4*>(&MoL[lbase + 1152 * p]) = So[p];
    }
    if (c < 31) {
#pragma unroll
      for (int p = 0; p < 8; ++p) {
        Sa[p] = *reinterpret_cast<const float4*>(gma + (size_t)(m0 + 16 + 2 * p) * 16384);
        So[p] = *reinterpret_cast<const float4*>(gmo + (size_t)(m0 + 16 + 2 * p) * 16384);
      }
#pragma unroll
      for (int j = 0; j < 16; ++j) rn[j] = rbase[(size_t)(m0 + 16 + j) * 512];
    }
    __syncthreads();
#pragma unroll
    for (int j = 0; j < 16; ++j) {
      float s = dot32(A, mabase + j * 576) * tmp;   // identical sequence to pass 1
      const int m = m0 + j;
      const int g = j & 7;
      float e;
      if ((rc[j] < 0.1f) | (m == gb)) e = 0.f;      // masked -> exact 0, like exp(-inf)
      else                            e = __expf(s - M[g]) * IL[g];
      wbase[(size_t)m * 512] = e;
      const float* vb = mobase + j * 576;
#pragma unroll
      for (int k = 0; k < 8; ++k) {
        float4 q = *reinterpret_cast<const float4*>(vb + 4 * k);
        O[k].x = fmaf(e, q.x, O[k].x);
        O[k].y = fmaf(e, q.y, O[k].y);
        O[k].z = fmaf(e, q.z, O[k].z);
        O[k].w = fmaf(e, q.w, O[k].w);
      }
    }
#pragma unroll
    for (int j = 0; j < 16; ++j) rc[j] = rn[j];
  }

  float* ob = outs + ((size_t)gb * 512 + gu) * 32;
#pragma unroll
  for (int k = 0; k < 8; ++k)
    *reinterpret_cast<float4*>(ob + 4 * k) = O[k];
}

extern "C" void kernel_launch(void* const* d_in, const int* in_sizes, int n_in,
                              void* d_out, int out_size, void* d_ws, size_t ws_size,
                              hipStream_t stream) {
  const float* x    = (const float*)d_in[0];   // [512][4096]
  const float* ma   = (const float*)d_in[1];   // [512][512][32]
  const float* mo   = (const float*)d_in[2];   // [512][512][32]
  const float* rnd  = (const float*)d_in[3];   // [512][512][512]
  const float* w1   = (const float*)d_in[4];   // [8][512][256]
  const float* b1   = (const float*)d_in[5];   // [8][256]
  const float* w2   = (const float*)d_in[6];   // [8][256][2048]
  const float* b2   = (const float*)d_in[7];   // [8][2048]
  const float* temp = (const float*)d_in[8];   // [512]

  float* out  = (float*)d_out;
  float* att  = out;                  // 8388608
  float* ga   = out + 8388608;        // 1048576
  float* wbuf = out + 9437184;        // 134217728
  float* outs = out + 143654912;      // 8388608

  gemm_split<<<dim3(32, 8), 256, 0, stream>>>(x, 4096, 512, w1, 256, b1, ga, 2048);
  gemm_split<<<dim3(256, 8), 256, 0, stream>>>(ga, 2048, 256, w2, 2048, b2, att, 16384);
  fused_back_kernel<<<dim3(1024), 256, 0, stream>>>(att, ma, mo, rnd, temp, wbuf, outs);
}

// Round 4
// 7145.657 us; speedup vs baseline: 1.1738x; 1.1738x over previous
//
#include <hip/hip_runtime.h>
#include <math.h>

#define NEGBIG (-1e30f)

// Sizes: B=512, S=8, U=512, D=32, G=8, DIM_IN=4096, DAG=2048
// out layout: att[512*16384] | ga[512*2048] | w[512^3] | outputs[512*16384]

// ---------------- K1/K2: per-split fp32 GEMM (64x64 tile, Kstep 16) ----------------
__global__ __launch_bounds__(256) void gemm_split(
    const float* __restrict__ A, int lda, int Ksz,
    const float* __restrict__ Bw, int NS,
    const float* __restrict__ bias,
    float* __restrict__ C, int ldc)
{
  const int n0 = blockIdx.x * 64;
  const int b0 = blockIdx.y * 64;
  const int s  = n0 / NS;
  const float* Bp = Bw + (size_t)s * Ksz * NS;
  const int nloc0 = n0 - s * NS;
  const int acol0 = s * Ksz;

  __shared__ float As[16][64];
  __shared__ float Bs[16][64];

  const int t  = threadIdx.x;
  const int tb = t & 15, tn = t >> 4;
  float acc[4][4] = {};

  for (int k0 = 0; k0 < Ksz; k0 += 16) {
    {
      int r = t & 63, g = t >> 6;
      float4 v = *reinterpret_cast<const float4*>(
          A + (size_t)(b0 + r) * lda + acol0 + k0 + 4 * g);
      As[4*g+0][r] = v.x; As[4*g+1][r] = v.y; As[4*g+2][r] = v.z; As[4*g+3][r] = v.w;
    }
    {
      int kk = t >> 4, n4 = t & 15;
      float4 v = *reinterpret_cast<const float4*>(
          Bp + (size_t)(k0 + kk) * NS + nloc0 + 4 * n4);
      *reinterpret_cast<float4*>(&Bs[kk][4*n4]) = v;
    }
    __syncthreads();
#pragma unroll
    for (int k = 0; k < 16; ++k) {
      float4 a4 = *reinterpret_cast<const float4*>(&As[k][4*tb]);
      float4 b4 = *reinterpret_cast<const float4*>(&Bs[k][4*tn]);
      float av[4] = {a4.x, a4.y, a4.z, a4.w};
      float bv[4] = {b4.x, b4.y, b4.z, b4.w};
#pragma unroll
      for (int i = 0; i < 4; ++i)
#pragma unroll
        for (int j = 0; j < 4; ++j)
          acc[i][j] = fmaf(av[i], bv[j], acc[i][j]);
    }
    __syncthreads();
  }
#pragma unroll
  for (int i = 0; i < 4; ++i) {
    int row = b0 + 4*tb + i;
    int col = n0 + 4*tn;
    float4 o;
    o.x = acc[i][0] + bias[col + 0];
    o.y = acc[i][1] + bias[col + 1];
    o.z = acc[i][2] + bias[col + 2];
    o.w = acc[i][3] + bias[col + 3];
    *reinterpret_cast<float4*>(C + (size_t)row * ldc + col) = o;
  }
}

// ---------------- fused back half, register-budgeted ----------------
// thread = (b,u). pass 1: stream m in chunks of 8, masked scores -> online (M,L),
// mask bits -> Msk LDS (per-thread words). pass 2: recompute identical score,
// w = exp(s-M)/(8L) (masked -> 0), accumulate outputs in regs.
// LDS: Ma/Mo chunk [8 m][16 u][36 f] (pad 36: reads 2-way max, 4-way u-broadcast
// across the b-lanes), Msk[16][256]. 52 KB -> 3 blocks/CU. ~140 VGPR -> no spill.

__device__ __forceinline__ float dot32(const float4 A[8], const float* base) {
  float s0 = 0.f, s1 = 0.f, s2 = 0.f, s3 = 0.f;
#pragma unroll
  for (int k = 0; k < 8; ++k) {
    float4 q = *reinterpret_cast<const float4*>(base + 4 * k);
    s0 = fmaf(A[k].x, q.x, s0);
    s1 = fmaf(A[k].y, q.y, s1);
    s2 = fmaf(A[k].z, q.z, s2);
    s3 = fmaf(A[k].w, q.w, s3);
  }
  return (s0 + s2) + (s1 + s3);
}

__global__ __launch_bounds__(256) void fused_back_kernel(
    const float* __restrict__ att, const float* __restrict__ ma,
    const float* __restrict__ mo, const float* __restrict__ rnd,
    const float* __restrict__ temp,
    float* __restrict__ w, float* __restrict__ outs)
{
  __shared__ float MaL[8 * 16 * 36];     // 18 KB
  __shared__ float MoL[8 * 16 * 36];     // 18 KB
  __shared__ unsigned Msk[16 * 256];     // 16 KB (per-thread indexed storage)

  const int bid = blockIdx.x;
  const int wk = ((bid & 7) << 7) | (bid >> 3);   // XCD-chunked (1024 % 8 == 0)
  const int b0 = (wk & 31) * 16, u0 = (wk >> 5) * 16;
  const int t = threadIdx.x;
  const int u = t & 15, tb = t >> 4;
  const int gb = b0 + tb, gu = u0 + u;

  float4 A[8];
  {
    const float* ar = att + ((size_t)gb * 512 + gu) * 32;
#pragma unroll
    for (int k = 0; k < 8; ++k)
      A[k] = *reinterpret_cast<const float4*>(ar + 4 * k);
  }
  const float tmp = temp[gu];
  const float* rbase = rnd + (size_t)gb * 262144 + gu;

  // staging ids: per thread 4 f4 (64B contiguous) per tensor per 8-m chunk
  const int half = t & 1, u_s = (t >> 1) & 15, m_s = t >> 5;
  const float* gma = ma + (size_t)m_s * 16384 + (size_t)(u0 + u_s) * 32 + half * 16;
  const float* gmo = mo + (size_t)m_s * 16384 + (size_t)(u0 + u_s) * 32 + half * 16;
  const int lb = (m_s * 16 + u_s) * 36 + half * 16;
  const float* mabase = &MaL[u * 36];    // + j*576 + 4k  (u-only -> lane broadcast)
  const float* mobase = &MoL[u * 36];

  float M[8], L[8];
#pragma unroll
  for (int g = 0; g < 8; ++g) { M[g] = NEGBIG; L[g] = 0.f; }

  // ---------------- pass 1: online stats + mask bits ----------------
  float4 Sa[4];
  float rc[8], rn[8] = {};
#pragma unroll
  for (int p = 0; p < 4; ++p)
    Sa[p] = *reinterpret_cast<const float4*>(gma + 4 * p);
#pragma unroll
  for (int j = 0; j < 8; ++j) rc[j] = rbase[(size_t)j * 512];

#pragma unroll 1
  for (int cw = 0; cw < 16; ++cw) {
    unsigned mw = 0;
#pragma unroll
    for (int c4 = 0; c4 < 4; ++c4) {
      const int c = cw * 4 + c4, m0 = c * 8;
      __syncthreads();                   // prev chunk's readers done
#pragma unroll
      for (int p = 0; p < 4; ++p)
        *reinterpret_cast<float4*>(&MaL[lb + 4 * p]) = Sa[p];
      __syncthreads();                   // LDS ready
      if (c < 63) {                      // loads fly across this chunk's compute
#pragma unroll
        for (int p = 0; p < 4; ++p)
          Sa[p] = *reinterpret_cast<const float4*>(gma + (size_t)(m0 + 8) * 16384 + 4 * p);
#pragma unroll
        for (int j = 0; j < 8; ++j) rn[j] = rbase[(size_t)(m0 + 8 + j) * 512];
      }
#pragma unroll
      for (int j = 0; j < 8; ++j) {      // g == j (m = 8c+j)
        float s = dot32(A, mabase + j * 576) * tmp;
        const int m = m0 + j;
        if ((rc[j] < 0.1f) | (m == gb)) { s = NEGBIG; mw |= (1u << (c4 * 8 + j)); }
        float d = s - M[j];
        if (d > 0.f) { L[j] = fmaf(L[j], __expf(-d), 1.f); M[j] = s; }
        else          L[j] += __expf(d);
      }
#pragma unroll
      for (int j = 0; j < 8; ++j) rc[j] = rn[j];
    }
    Msk[cw * 256 + t] = mw;
  }

  float IL[8];
#pragma unroll
  for (int g = 0; g < 8; ++g) IL[g] = 1.0f / (8.0f * L[g]);

  // ---------------- pass 2: w emit + outputs ----------------
  float4 O[8];
#pragma unroll
  for (int k = 0; k < 8; ++k) O[k] = make_float4(0.f, 0.f, 0.f, 0.f);
  float4 So[4];
#pragma unroll
  for (int p = 0; p < 4; ++p) {
    Sa[p] = *reinterpret_cast<const float4*>(gma + 4 * p);
    So[p] = *reinterpret_cast<const float4*>(gmo + 4 * p);
  }
  float* wbase = w + (size_t)gb * 262144 + gu;

#pragma unroll 1
  for (int cw = 0; cw < 16; ++cw) {
    const unsigned mw = Msk[cw * 256 + t];
#pragma unroll
    for (int c4 = 0; c4 < 4; ++c4) {
      const int c = cw * 4 + c4, m0 = c * 8;
      __syncthreads();
#pragma unroll
      for (int p = 0; p < 4; ++p) {
        *reinterpret_cast<float4*>(&MaL[lb + 4 * p]) = Sa[p];
        *reinterpret_cast<float4*>(&MoL[lb + 4 * p]) = So[p];
      }
      __syncthreads();
      if (c < 63) {
#pragma unroll
        for (int p = 0; p < 4; ++p) {
          Sa[p] = *reinterpret_cast<const float4*>(gma + (size_t)(m0 + 8) * 16384 + 4 * p);
          So[p] = *reinterpret_cast<const float4*>(gmo + (size_t)(m0 + 8) * 16384 + 4 * p);
        }
      }
#pragma unroll
      for (int j = 0; j < 8; ++j) {
        float s = dot32(A, mabase + j * 576) * tmp;   // identical sequence to pass 1
        float e = ((mw >> (c4 * 8 + j)) & 1u) ? 0.f
                                              : __expf(s - M[j]) * IL[j];
        wbase[(size_t)(m0 + j) * 512] = e;
        const float* vb = mobase + j * 576;
#pragma unroll
        for (int k = 0; k < 8; ++k) {
          float4 q = *reinterpret_cast<const float4*>(vb + 4 * k);
          O[k].x = fmaf(e, q.x, O[k].x);
          O[k].y = fmaf(e, q.y, O[k].y);
          O[k].z = fmaf(e, q.z, O[k].z);
          O[k].w = fmaf(e, q.w, O[k].w);
        }
      }
    }
  }

  float* ob = outs + ((size_t)gb * 512 + gu) * 32;
#pragma unroll
  for (int k = 0; k < 8; ++k)
    *reinterpret_cast<float4*>(ob + 4 * k) = O[k];
}

extern "C" void kernel_launch(void* const* d_in, const int* in_sizes, int n_in,
                              void* d_out, int out_size, void* d_ws, size_t ws_size,
                              hipStream_t stream) {
  const float* x    = (const float*)d_in[0];   // [512][4096]
  const float* ma   = (const float*)d_in[1];   // [512][512][32]
  const float* mo   = (const float*)d_in[2];   // [512][512][32]
  const float* rnd  = (const float*)d_in[3];   // [512][512][512]
  const float* w1   = (const float*)d_in[4];   // [8][512][256]
  const float* b1   = (const float*)d_in[5];   // [8][256]
  const float* w2   = (const float*)d_in[6];   // [8][256][2048]
  const float* b2   = (const float*)d_in[7];   // [8][2048]
  const float* temp = (const float*)d_in[8];   // [512]

  float* out  = (float*)d_out;
  float* att  = out;                  // 8388608
  float* ga   = out + 8388608;        // 1048576
  float* wbuf = out + 9437184;        // 134217728
  float* outs = out + 143654912;      // 8388608

  gemm_split<<<dim3(32, 8), 256, 0, stream>>>(x, 4096, 512, w1, 256, b1, ga, 2048);
  gemm_split<<<dim3(256, 8), 256, 0, stream>>>(ga, 2048, 256, w2, 2048, b2, att, 16384);
  fused_back_kernel<<<dim3(1024), 256, 0, stream>>>(att, ma, mo, rnd, temp, wbuf, outs);
}

// Round 5
// 830.881 us; speedup vs baseline: 10.0947x; 8.6001x over previous
//
#include <hip/hip_runtime.h>
#include <math.h>

#define NEGBIG (-1e30f)

// Sizes: B=512, S=8, U=512, D=32, G=8, DIM_IN=4096, DAG=2048
// out layout: att[512*16384] | ga[512*2048] | w[512^3] | outputs[512*16384]
// outs region doubles as stats scratch between K3a and K3b: cell (b,u) floats
// [0..7]=M per group, [8..15]=1/(8L). Written by one K3a block, read then fully
// overwritten by exactly one K3b block -> no hazard, fully rewritten every call.

// ---------------- K1/K2: per-split fp32 GEMM (64x64 tile, Kstep 16) ----------------
__global__ __launch_bounds__(256) void gemm_split(
    const float* __restrict__ A, int lda, int Ksz,
    const float* __restrict__ Bw, int NS,
    const float* __restrict__ bias,
    float* __restrict__ C, int ldc)
{
  const int n0 = blockIdx.x * 64;
  const int b0 = blockIdx.y * 64;
  const int s  = n0 / NS;
  const float* Bp = Bw + (size_t)s * Ksz * NS;
  const int nloc0 = n0 - s * NS;
  const int acol0 = s * Ksz;

  __shared__ float As[16][64];
  __shared__ float Bs[16][64];

  const int t  = threadIdx.x;
  const int tb = t & 15, tn = t >> 4;
  float acc[4][4] = {};

  for (int k0 = 0; k0 < Ksz; k0 += 16) {
    {
      int r = t & 63, g = t >> 6;
      float4 v = *reinterpret_cast<const float4*>(
          A + (size_t)(b0 + r) * lda + acol0 + k0 + 4 * g);
      As[4*g+0][r] = v.x; As[4*g+1][r] = v.y; As[4*g+2][r] = v.z; As[4*g+3][r] = v.w;
    }
    {
      int kk = t >> 4, n4 = t & 15;
      float4 v = *reinterpret_cast<const float4*>(
          Bp + (size_t)(k0 + kk) * NS + nloc0 + 4 * n4);
      *reinterpret_cast<float4*>(&Bs[kk][4*n4]) = v;
    }
    __syncthreads();
#pragma unroll
    for (int k = 0; k < 16; ++k) {
      float4 a4 = *reinterpret_cast<const float4*>(&As[k][4*tb]);
      float4 b4 = *reinterpret_cast<const float4*>(&Bs[k][4*tn]);
      float av[4] = {a4.x, a4.y, a4.z, a4.w};
      float bv[4] = {b4.x, b4.y, b4.z, b4.w};
#pragma unroll
      for (int i = 0; i < 4; ++i)
#pragma unroll
        for (int j = 0; j < 4; ++j)
          acc[i][j] = fmaf(av[i], bv[j], acc[i][j]);
    }
    __syncthreads();
  }
#pragma unroll
  for (int i = 0; i < 4; ++i) {
    int row = b0 + 4*tb + i;
    int col = n0 + 4*tn;
    float4 o;
    o.x = acc[i][0] + bias[col + 0];
    o.y = acc[i][1] + bias[col + 1];
    o.z = acc[i][2] + bias[col + 2];
    o.w = acc[i][3] + bias[col + 3];
    *reinterpret_cast<float4*>(C + (size_t)row * ldc + col) = o;
  }
}

// ---------------- K3a: masked raw scores + online group stats (round-2 version) ----
__global__ __launch_bounds__(256) void scores_stats_kernel(
    const float* __restrict__ att,   // [512][512][32]
    const float* __restrict__ ma,    // [512][512][32]
    const float* __restrict__ rnd,   // [512][512][512]
    const float* __restrict__ temp,  // [512]
    float* __restrict__ wout,        // [512][512][512] raw masked scores
    float* __restrict__ stats)       // outs region base
{
  __shared__ float At[16 * 516];
  __shared__ float Ma[16 * 260];
  const int b0 = blockIdx.x * 16;
  const int u0 = blockIdx.y * 16;
  const int t  = threadIdx.x;
  const int u  = t & 15, tb = (t >> 4) & 3, tm = t >> 6;

  {  // stage att tile once
    int r = t >> 4, base = t & 15;
    const float* src = att + (size_t)(b0 + r) * 16384 + u0 * 32;
#pragma unroll
    for (int g = 0; g < 8; ++g) {
      int i4 = base + 16 * g;
      int uu = i4 >> 3, d4 = i4 & 7;
      float4 v = *reinterpret_cast<const float4*>(src + 4 * i4);
      *reinterpret_cast<float4*>(&At[uu*516 + d4*64 + (r ^ ((2*d4) & 15))*4]) = v;
    }
  }
  const float tmp = temp[u0 + u];
  float Ms[4][2], Ls[4][2];
#pragma unroll
  for (int i = 0; i < 4; ++i)
#pragma unroll
    for (int j = 0; j < 2; ++j) { Ms[i][j] = NEGBIG; Ls[i][j] = 0.f; }

  for (int m0 = 0; m0 < 512; m0 += 8) {
    float rv[4][2];
#pragma unroll
    for (int i = 0; i < 4; ++i)
#pragma unroll
      for (int j = 0; j < 2; ++j)
        rv[i][j] = rnd[((size_t)(b0 + 4*tb + i) * 512 + m0 + 2*tm + j) * 512 + u0 + u];
    __syncthreads();
    {  // stage 8 ma rows
      int r = t >> 5, base = t & 31;
      const float* src = ma + (size_t)(m0 + r) * 16384 + u0 * 32;
#pragma unroll
      for (int g = 0; g < 4; ++g) {
        int i4 = base + 32 * g;
        int uu = i4 >> 3, d4 = i4 & 7;
        float4 v = *reinterpret_cast<const float4*>(src + 4 * i4);
        *reinterpret_cast<float4*>(&Ma[uu*260 + d4*32 + ((r ^ d4) & 7)*4]) = v;
      }
    }
    __syncthreads();
    float acc[4][2] = {};
#pragma unroll
    for (int d4 = 0; d4 < 8; ++d4) {
      const int sw = (2*d4) & 15;
      float4 av[4], mv[2];
#pragma unroll
      for (int i = 0; i < 4; ++i)
        av[i] = *reinterpret_cast<const float4*>(&At[u*516 + d4*64 + ((4*tb+i) ^ sw)*4]);
#pragma unroll
      for (int j = 0; j < 2; ++j)
        mv[j] = *reinterpret_cast<const float4*>(&Ma[u*260 + d4*32 + (((2*tm+j) ^ d4) & 7)*4]);
#pragma unroll
      for (int i = 0; i < 4; ++i)
#pragma unroll
        for (int j = 0; j < 2; ++j) {
          acc[i][j] = fmaf(av[i].x, mv[j].x, acc[i][j]);
          acc[i][j] = fmaf(av[i].y, mv[j].y, acc[i][j]);
          acc[i][j] = fmaf(av[i].z, mv[j].z, acc[i][j]);
          acc[i][j] = fmaf(av[i].w, mv[j].w, acc[i][j]);
        }
    }
#pragma unroll
    for (int i = 0; i < 4; ++i)
#pragma unroll
      for (int j = 0; j < 2; ++j) {
        int gb = b0 + 4*tb + i, gm = m0 + 2*tm + j;
        float s = acc[i][j] * tmp;
        if ((rv[i][j] < 0.1f) | (gm == gb)) s = NEGBIG;
        wout[((size_t)gb * 512 + gm) * 512 + u0 + u] = s;
        float d = s - Ms[i][j];
        if (d > 0.f) { Ls[i][j] = fmaf(Ls[i][j], __expf(-d), 1.f); Ms[i][j] = s; }
        else          Ls[i][j] += __expf(d);
      }
  }
#pragma unroll
  for (int i = 0; i < 4; ++i)
#pragma unroll
    for (int j = 0; j < 2; ++j) {
      int b = b0 + 4*tb + i, g = 2*tm + j;
      float* cell = stats + ((size_t)b * 512 + u0 + u) * 32;
      cell[g]     = Ms[i][j];
      cell[8 + g] = 1.0f / (8.0f * Ls[i][j]);
    }
}

// ---------------- K3b v2: w = exp(s-M)/(8L) + outputs, 16b x 16u blocks ----------
// grid (32 u-tiles, 32 b-tiles) = 1024 blocks (4/CU). m-chunks of 8: group g == m-lane,
// so per-thread stats are 16 regs loaded once. Register double-buffer of w-rows and
// the mo slab (prefetch issued at phase-B start -> drained one full phase later).
// LDS: MoL [8m][16u][8 d-slots XOR u&7] 16 KB (linear writes, 2-way reads),
//      E [8m][16u][16b pad 17] 8.7 KB. Total 25 KB.
__global__ __launch_bounds__(256) void emit_outputs_v2(
    const float* __restrict__ mo,    // [512][512][32]
    float* __restrict__ w,           // in: raw scores, out: final w
    float* __restrict__ outs)        // in: stats cells, out: outputs [512][512][32]
{
  __shared__ float MoL[8 * 16 * 32];
  __shared__ float E[8 * 16 * 17];
  const int u0 = blockIdx.x * 16;
  const int b0 = blockIdx.y * 16;
  const int t  = threadIdx.x;
  // phase A ids: 16 b x 8 m x 2 u-halves
  const int ab = t >> 4, am = (t >> 1) & 7, uh = t & 1;
  // phase B ids: 16 u x 4 b-quads x 4 d-quarters
  const int pu = t >> 4, bq = (t >> 2) & 3, dh = t & 3;

  // stats for (b=ab, u=u0+uh*8+j, g=am) -- g == m-lane since chunks are 8-aligned
  float Mreg[8], Sreg[8];
  {
    const float* cb = outs + ((size_t)(b0 + ab) * 512 + u0 + uh * 8) * 32;
#pragma unroll
    for (int j = 0; j < 8; ++j) {
      Mreg[j] = cb[j * 32 + am];
      Sreg[j] = cb[j * 32 + 8 + am];
    }
  }

  float4 acc[4][2];
#pragma unroll
  for (int i = 0; i < 4; ++i) {
    acc[i][0] = make_float4(0.f, 0.f, 0.f, 0.f);
    acc[i][1] = make_float4(0.f, 0.f, 0.f, 0.f);
  }

  float* wbase = w + (size_t)(b0 + ab) * 262144 + u0 + uh * 8;   // + m*512

  // mo staging: piece P = k*256 + t of the 4096-float chunk slab;
  // slab float F = P*4 holds mo[mc+m][u0+u][(dq ^ (u&7))*4 ..] with
  // m = P>>7, u = (P>>3)&15, dq = P&7  (linear LDS writes, swizzled source)
  const float* msrc0;  const float* msrc1;  const float* msrc2;  const float* msrc3;
  int loff0, loff1, loff2, loff3;
  {
    int P, mm, uu, dq;
    P = t;          mm = P >> 7; uu = (P >> 3) & 15; dq = P & 7;
    msrc0 = mo + (size_t)mm * 16384 + (size_t)(u0 + uu) * 32 + (dq ^ (uu & 7)) * 4;
    loff0 = P * 4;
    P = 256 + t;    mm = P >> 7; uu = (P >> 3) & 15; dq = P & 7;
    msrc1 = mo + (size_t)mm * 16384 + (size_t)(u0 + uu) * 32 + (dq ^ (uu & 7)) * 4;
    loff1 = P * 4;
    P = 512 + t;    mm = P >> 7; uu = (P >> 3) & 15; dq = P & 7;
    msrc2 = mo + (size_t)mm * 16384 + (size_t)(u0 + uu) * 32 + (dq ^ (uu & 7)) * 4;
    loff2 = P * 4;
    P = 768 + t;    mm = P >> 7; uu = (P >> 3) & 15; dq = P & 7;
    msrc3 = mo + (size_t)mm * 16384 + (size_t)(u0 + uu) * 32 + (dq ^ (uu & 7)) * 4;
    loff3 = P * 4;
  }

  // prologue: chunk 0 into regs
  float4 wpre0, wpre1, smo0, smo1, smo2, smo3;
  {
    const float* wp = wbase + (size_t)am * 512;
    wpre0 = *reinterpret_cast<const float4*>(wp);
    wpre1 = *reinterpret_cast<const float4*>(wp + 4);
    smo0 = *reinterpret_cast<const float4*>(msrc0);
    smo1 = *reinterpret_cast<const float4*>(msrc1);
    smo2 = *reinterpret_cast<const float4*>(msrc2);
    smo3 = *reinterpret_cast<const float4*>(msrc3);
  }

#pragma unroll 1
  for (int c = 0; c < 64; ++c) {
    const int mc = c * 8;
    if (c) __syncthreads();            // phase B of c-1 done with E/MoL

    // ---- phase A: e = exp(s-M)*S, write w + E; ds_write staged mo ----
    {
      float* wp = wbase + (size_t)(mc + am) * 512;
      float s0[4] = {wpre0.x, wpre0.y, wpre0.z, wpre0.w};
      float s1[4] = {wpre1.x, wpre1.y, wpre1.z, wpre1.w};
#pragma unroll
      for (int e2 = 0; e2 < 4; ++e2) {
        float v = __expf(s0[e2] - Mreg[e2]) * Sreg[e2];
        s0[e2] = v;
        E[(am * 16 + uh * 8 + e2) * 17 + ab] = v;
      }
#pragma unroll
      for (int e2 = 0; e2 < 4; ++e2) {
        float v = __expf(s1[e2] - Mreg[4 + e2]) * Sreg[4 + e2];
        s1[e2] = v;
        E[(am * 16 + uh * 8 + 4 + e2) * 17 + ab] = v;
      }
      *reinterpret_cast<float4*>(wp)     = make_float4(s0[0], s0[1], s0[2], s0[3]);
      *reinterpret_cast<float4*>(wp + 4) = make_float4(s1[0], s1[1], s1[2], s1[3]);
    }
    *reinterpret_cast<float4*>(&MoL[loff0]) = smo0;
    *reinterpret_cast<float4*>(&MoL[loff1]) = smo1;
    *reinterpret_cast<float4*>(&MoL[loff2]) = smo2;
    *reinterpret_cast<float4*>(&MoL[loff3]) = smo3;
    __syncthreads();                   // E + MoL ready

    // ---- issue prefetch for chunk c+1 (consumed after next loop-top barrier) ----
    if (c < 63) {
      const float* wp = wbase + (size_t)(mc + 8 + am) * 512;
      wpre0 = *reinterpret_cast<const float4*>(wp);
      wpre1 = *reinterpret_cast<const float4*>(wp + 4);
      const size_t moff = (size_t)(mc + 8) * 16384;
      smo0 = *reinterpret_cast<const float4*>(msrc0 + moff);
      smo1 = *reinterpret_cast<const float4*>(msrc1 + moff);
      smo2 = *reinterpret_cast<const float4*>(msrc2 + moff);
      smo3 = *reinterpret_cast<const float4*>(msrc3 + moff);
    }

    // ---- phase B: acc[4b][8d] += E[m][pu][4b] * Mo[m][pu][8d] ----
#pragma unroll
    for (int m = 0; m < 8; ++m) {
      float4 ef = *reinterpret_cast<const float4*>(&E[(m * 16 + pu) * 17 + 4 * bq]);
      float4 v0 = *reinterpret_cast<const float4*>(
          &MoL[(m * 16 + pu) * 32 + (((2 * dh) ^ (pu & 7)) * 4)]);
      float4 v1 = *reinterpret_cast<const float4*>(
          &MoL[(m * 16 + pu) * 32 + (((2 * dh + 1) ^ (pu & 7)) * 4)]);
      float es[4] = {ef.x, ef.y, ef.z, ef.w};
#pragma unroll
      for (int i = 0; i < 4; ++i) {
        acc[i][0].x = fmaf(es[i], v0.x, acc[i][0].x);
        acc[i][0].y = fmaf(es[i], v0.y, acc[i][0].y);
        acc[i][0].z = fmaf(es[i], v0.z, acc[i][0].z);
        acc[i][0].w = fmaf(es[i], v0.w, acc[i][0].w);
        acc[i][1].x = fmaf(es[i], v1.x, acc[i][1].x);
        acc[i][1].y = fmaf(es[i], v1.y, acc[i][1].y);
        acc[i][1].z = fmaf(es[i], v1.z, acc[i][1].z);
        acc[i][1].w = fmaf(es[i], v1.w, acc[i][1].w);
      }
    }
  }

  // epilogue: overwrite stats cells with final outputs
#pragma unroll
  for (int i = 0; i < 4; ++i) {
    float* dst = outs + ((size_t)(b0 + 4 * bq + i) * 512 + u0 + pu) * 32 + 8 * dh;
    *reinterpret_cast<float4*>(dst)     = acc[i][0];
    *reinterpret_cast<float4*>(dst + 4) = acc[i][1];
  }
}

extern "C" void kernel_launch(void* const* d_in, const int* in_sizes, int n_in,
                              void* d_out, int out_size, void* d_ws, size_t ws_size,
                              hipStream_t stream) {
  const float* x    = (const float*)d_in[0];   // [512][4096]
  const float* ma   = (const float*)d_in[1];   // [512][512][32]
  const float* mo   = (const float*)d_in[2];   // [512][512][32]
  const float* rnd  = (const float*)d_in[3];   // [512][512][512]
  const float* w1   = (const float*)d_in[4];   // [8][512][256]
  const float* b1   = (const float*)d_in[5];   // [8][256]
  const float* w2   = (const float*)d_in[6];   // [8][256][2048]
  const float* b2   = (const float*)d_in[7];   // [8][2048]
  const float* temp = (const float*)d_in[8];   // [512]

  float* out  = (float*)d_out;
  float* att  = out;                  // 8388608
  float* ga   = out + 8388608;        // 1048576
  float* wbuf = out + 9437184;        // 134217728
  float* outs = out + 143654912;      // 8388608

  gemm_split<<<dim3(32, 8), 256, 0, stream>>>(x, 4096, 512, w1, 256, b1, ga, 2048);
  gemm_split<<<dim3(256, 8), 256, 0, stream>>>(ga, 2048, 256, w2, 2048, b2, att, 16384);
  scores_stats_kernel<<<dim3(32, 32), 256, 0, stream>>>(att, ma, rnd, temp, wbuf, outs);
  emit_outputs_v2<<<dim3(32, 32), 256, 0, stream>>>(mo, wbuf, outs);
}